// Round 11
// baseline (128.724 us; speedup 1.0000x reference)
//
#include <hip/hip_runtime.h>
#include <hip/hip_bf16.h>

// Problem constants (B=2, T=4096, D=1024, H=16, HD=64, W=16)
#define D_MODEL 1024
#define SEQ_T   4096
#define NBATCH  2
#define NHEADS  16
#define HEAD_D  64
#define WIN     16

typedef __attribute__((ext_vector_type(8))) short bf16x8;           // MFMA A/B frag
typedef __attribute__((ext_vector_type(8))) unsigned short u16x8;   // 16B bf16 load
typedef __attribute__((ext_vector_type(4))) float f32x4;            // MFMA C/D frag

__device__ __forceinline__ unsigned short f2bf(float f) {
  union { float f; unsigned int u; } v; v.f = f;
  unsigned int r = v.u + 0x7fffu + ((v.u >> 16) & 1u);  // RNE
  return (unsigned short)(r >> 16);
}
__device__ __forceinline__ float bf2f(unsigned short u) {
  union { unsigned int u; float f; } v; v.u = ((unsigned int)u) << 16;
  return v.f;
}

#define SBAR() __builtin_amdgcn_s_barrier()
#define LGKM0() asm volatile("s_waitcnt lgkmcnt(0)" ::: "memory")
#define VMC(n) asm volatile("s_waitcnt vmcnt(" #n ")" ::: "memory")

// ---------------------------------------------------------------- merged cast kernel
__global__ __launch_bounds__(256) void cast_all(const float4* __restrict__ x,
                                                const float4* __restrict__ wq,
                                                const float4* __restrict__ wkv,
                                                const float4* __restrict__ wo,
                                                ushort* __restrict__ xb,
                                                ushort* __restrict__ wb) {
  int i = blockIdx.x * 256 + threadIdx.x;  // 0..3145727 float4 units
  float4 v;
  ushort* dst;
  if (i < 2097152) {
    v = x[i];
    dst = xb + (size_t)i * 4;
  } else {
    int j = i - 2097152;  // 0..1048575
    const float4* src;
    int off;
    if (j < 262144) { src = wq; off = 0; }
    else if (j < 786432) { src = wkv; off = 262144; }
    else { src = wo; off = 786432; }
    v = src[j - off];
    dst = wb + (size_t)j * 4;
  }
  ushort4 o;
  o.x = f2bf(v.x); o.y = f2bf(v.y); o.z = f2bf(v.z); o.w = f2bf(v.w);
  *(ushort4*)dst = o;
}

// ---------------------------------------------------------------- 256x128 GEMM, triple-buffered LDS
// C[m,n] = sum_k A[m,k]*Bt[n,k]; bf16 in. 8 waves 4Mx2N (per-wave 64x64).
// LDS 144KiB: A bufs 3x32KB @0, B bufs 3x16KB @98304. Chunk-XOR swizzle both-sides.
// ONE barrier + ONE vmcnt per K-tile; every wait is on loads issued >=2 K-tiles ago:
//   P0(t): read A(8)+B-lo(4) from buf[t%3]; STAGE_B(t+2 -> buf b2); lgkm0; 16 MFMA acc[0]
//   P1(t): read B-hi(4);                    STAGE_A(t+2 -> buf b2); lgkm0; 16 MFMA acc[1];
//          vmcnt(6)  [FIFO: B(t+1),A(t+1),B(t+2),A(t+2) -> retires tile t+1]; s_barrier
// Region safety: stage dest buf b2 holds tile t-1, last read P0/P1(t-1), certified by the
// single barrier at P1(t-1)-exit. Reads of tile t certified by vmcnt(6)+barrier at P1(t-1).
// Prologue: A0,B0,B1,A1 (12 loads/thread); vmcnt(6) retires A0,B0 -> FIFO {B1,A1} = steady.
// Tail: clamped kt restages identical bytes into the rotating free buffer (never re-read).
// EPI=0: bf16 store. EPI=1: Cb[idx] = bf16(acc + bf2f(residb[idx])).
template <int EPI>
__global__ __launch_bounds__(512, 2) void gemm_3buf(const ushort* __restrict__ A,
                                                    const ushort* __restrict__ Bt,
                                                    ushort* __restrict__ Cb,
                                                    const ushort* __restrict__ residb,
                                                    int M, int N, int K) {
  extern __shared__ char smem[];  // 147456 bytes
  const int NTK = K >> 6;
  const int tid = threadIdx.x;
  const int wid = tid >> 6;
  const int lane = tid & 63;
  const int m0 = blockIdx.y * 256;
  const int n0 = blockIdx.x * 128;

  // staging lane geometry (pre-swizzled source chunk; involution c ^= row&7)
  const int l8 = lane >> 3;
  const int lchunk = (lane & 7) ^ (l8 & 7);
  const ushort* pA = A + (size_t)(m0 + wid * 8 + l8) * K + lchunk * 8;
  const ushort* pB = Bt + (size_t)(n0 + wid * 8 + l8) * K + lchunk * 8;

// A tile 256x64 = 32 segs of 8 rows; per-wave 4 (j*8+wid). Linear LDS dest (m104).
#define STAGE_A(kt, db)                                                                    \
  {                                                                                        \
    _Pragma("unroll") for (int j = 0; j < 4; ++j) {                                        \
      const ushort* gp = pA + (size_t)(j * 64) * K + (size_t)(kt) * 64;                    \
      char* lp = smem + (db) * 32768 + (j * 8 + wid) * 1024;                               \
      __builtin_amdgcn_global_load_lds((const __attribute__((address_space(1))) void*)gp,  \
                                       (__attribute__((address_space(3))) void*)lp, 16, 0, 0); \
    }                                                                                      \
  }
// B tile 128x64 = 16 segs; per-wave 2.
#define STAGE_B(kt, db)                                                                    \
  {                                                                                        \
    _Pragma("unroll") for (int j = 0; j < 2; ++j) {                                        \
      const ushort* gp = pB + (size_t)(j * 64) * K + (size_t)(kt) * 64;                    \
      char* lp = smem + 98304 + (db) * 16384 + (j * 8 + wid) * 1024;                       \
      __builtin_amdgcn_global_load_lds((const __attribute__((address_space(1))) void*)gp,  \
                                       (__attribute__((address_space(3))) void*)lp, 16, 0, 0); \
    }                                                                                      \
  }

  // compute-side lane geometry
  const int fr = lane & 15;
  const int g = lane >> 4;
  const int wr = wid >> 1;   // 0..3 (64-row band)
  const int wc = wid & 1;    // 0..1 (64-col band)
  int aRow[4], bRow[2][2], ch[2];
#pragma unroll
  for (int mi = 0; mi < 4; ++mi) aRow[mi] = (wr * 64 + mi * 16 + fr) * 128;
#pragma unroll
  for (int nq = 0; nq < 2; ++nq)
#pragma unroll
    for (int ni = 0; ni < 2; ++ni) bRow[nq][ni] = (wc * 64 + nq * 32 + ni * 16 + fr) * 128;
#pragma unroll
  for (int kk = 0; kk < 2; ++kk) ch[kk] = ((kk * 4 + g) ^ (fr & 7)) * 16;

  f32x4 acc[2][4][2];
#pragma unroll
  for (int nq = 0; nq < 2; ++nq)
#pragma unroll
    for (int mi = 0; mi < 4; ++mi)
#pragma unroll
      for (int ni = 0; ni < 2; ++ni) acc[nq][mi][ni] = (f32x4){0.f, 0.f, 0.f, 0.f};

  bf16x8 a[4][2], b0[2][2], b1[2][2];

  // ---- prologue: A(0)->buf0, B(0)->buf0, B(1)->buf1, A(1)->buf1; vmcnt(6); barrier
  STAGE_A(0, 0); STAGE_B(0, 0); STAGE_B(1, 1); STAGE_A(1, 1);
  VMC(6);
  SBAR();

#define PHASE_MFMA(nq, bfr)                                                    \
  __builtin_amdgcn_s_setprio(1);                                               \
  _Pragma("unroll") for (int kk = 0; kk < 2; ++kk)                             \
    _Pragma("unroll") for (int mi = 0; mi < 4; ++mi)                           \
      _Pragma("unroll") for (int ni = 0; ni < 2; ++ni)                         \
        acc[nq][mi][ni] = __builtin_amdgcn_mfma_f32_16x16x32_bf16(             \
            a[mi][kk], bfr[ni][kk], acc[nq][mi][ni], 0, 0, 0);                 \
  __builtin_amdgcn_s_setprio(0);

  int cur = 0, nxt = 1, far = 2;  // rotating buffer ids: cur = t%3, far = (t+2)%3
#pragma unroll 1
  for (int t = 0; t < NTK; ++t) {
    const int u2 = (t + 2 < NTK) ? t + 2 : NTK - 1;  // clamped source k-tile
    const char* Ab = smem + cur * 32768;
    const char* Bb = smem + 98304 + cur * 16384;

    // ---- P0: read A (8) + B-lo (4); stage B(u2) -> far
#pragma unroll
    for (int mi = 0; mi < 4; ++mi)
#pragma unroll
      for (int kk = 0; kk < 2; ++kk)
        a[mi][kk] = *(const bf16x8*)(Ab + aRow[mi] + ch[kk]);
#pragma unroll
    for (int ni = 0; ni < 2; ++ni)
#pragma unroll
      for (int kk = 0; kk < 2; ++kk)
        b0[ni][kk] = *(const bf16x8*)(Bb + bRow[0][ni] + ch[kk]);
    STAGE_B(u2, far);
    LGKM0();
    PHASE_MFMA(0, b0);

    // ---- P1: read B-hi (4); stage A(u2) -> far; single vmcnt + barrier
#pragma unroll
    for (int ni = 0; ni < 2; ++ni)
#pragma unroll
      for (int kk = 0; kk < 2; ++kk)
        b1[ni][kk] = *(const bf16x8*)(Bb + bRow[1][ni] + ch[kk]);
    STAGE_A(u2, far);
    LGKM0();
    PHASE_MFMA(1, b1);
    VMC(6);
    SBAR();

    const int tmp = cur; cur = nxt; nxt = far; far = tmp;
  }

  // ---- epilogue: C/D layout col=lane&15, row=(lane>>4)*4+r
  const int cc = lane & 15;
  const int cr4 = (lane >> 4) * 4;
#pragma unroll
  for (int nq = 0; nq < 2; ++nq)
#pragma unroll
    for (int mi = 0; mi < 4; ++mi)
#pragma unroll
      for (int ni = 0; ni < 2; ++ni)
#pragma unroll
        for (int r = 0; r < 4; ++r) {
          int row = m0 + wr * 64 + mi * 16 + cr4 + r;
          int col = n0 + wc * 64 + nq * 32 + ni * 16 + cc;
          size_t idx = (size_t)row * N + col;
          float v = acc[nq][mi][ni][r];
          if (EPI == 0) {
            Cb[idx] = f2bf(v);
          } else {
            Cb[idx] = f2bf(v + bf2f(residb[idx]));
          }
        }
#undef STAGE_A
#undef STAGE_B
#undef PHASE_MFMA
}

// ---------------------------------------------------------------- sliding-window attention (MFMA band)
__global__ __launch_bounds__(256) void attn_win_mfma(const ushort* __restrict__ qkv,
                                                     ushort* __restrict__ msg) {
  __shared__ ushort Ks[80][72];
  __shared__ ushort Vt[64][88];
  __shared__ ushort Ps[4][16][40];

  const int tile = blockIdx.x;
  const int h = blockIdx.y;
  const int b = blockIdx.z;
  const int t0 = tile * 64;
  const size_t rowbase = (size_t)b * SEQ_T;
  const int tid = threadIdx.x;
  const int wave = tid >> 6;
  const int lane = tid & 63;

  for (int chunk = tid; chunk < 1280; chunk += 256) {
    int r = chunk >> 4;
    int c = (chunk & 15) * 8;
    int t = t0 - 16 + r;
    u16x8 u = {0, 0, 0, 0, 0, 0, 0, 0};
    if (t >= 0)
      u = *(const u16x8*)(qkv + (rowbase + t) * 3072 + 1024 + (size_t)h * 128 + c);
    if (c < 64) {
      *(u16x8*)&Ks[r][c] = u;
    } else {
      int d0 = c - 64;
#pragma unroll
      for (int j = 0; j < 8; ++j) Vt[d0 + j][r] = u[j];
    }
  }
  __syncthreads();

  const int fr = lane & 15;
  const int g = lane >> 4;
  const int rbase = wave * 16;

  bf16x8 qa[2];
#pragma unroll
  for (int kk = 0; kk < 2; ++kk)
    qa[kk] = *(const bf16x8*)(qkv + (rowbase + t0 + wave * 16 + fr) * 3072 +
                              (size_t)h * 64 + kk * 32 + g * 8);

  f32x4 sacc[2];
  sacc[0] = (f32x4){0.f, 0.f, 0.f, 0.f};
  sacc[1] = (f32x4){0.f, 0.f, 0.f, 0.f};
#pragma unroll
  for (int kk = 0; kk < 2; ++kk) {
#pragma unroll
    for (int nt = 0; nt < 2; ++nt) {
      bf16x8 kb = *(const bf16x8*)&Ks[rbase + nt * 16 + fr][kk * 32 + g * 8];
      sacc[nt] = __builtin_amdgcn_mfma_f32_16x16x32_bf16(qa[kk], kb, sacc[nt], 0, 0, 0);
    }
  }

#pragma unroll
  for (int nt = 0; nt < 2; ++nt) {
    int tk = t0 - 16 + rbase + nt * 16 + fr;
#pragma unroll
    for (int reg = 0; reg < 4; ++reg) {
      int t = t0 + wave * 16 + g * 4 + reg;
      float tau = 0.f;
      if (tk >= 0 && tk >= t - WIN && tk <= t - 1)
        tau = 1.f / (1.f + __expf(-sacc[nt][reg] * 0.125f));
      Ps[wave][g * 4 + reg][nt * 16 + fr] = f2bf(tau);
    }
  }
  __syncthreads();

  bf16x8 pa = *(const bf16x8*)&Ps[wave][fr][g * 8];
#pragma unroll
  for (int ct = 0; ct < 4; ++ct) {
    bf16x8 vb = *(const bf16x8*)&Vt[ct * 16 + fr][rbase + g * 8];
    f32x4 m = __builtin_amdgcn_mfma_f32_16x16x32_bf16(pa, vb, (f32x4){0.f, 0.f, 0.f, 0.f}, 0, 0, 0);
#pragma unroll
    for (int reg = 0; reg < 4; ++reg) {
      int t = t0 + wave * 16 + g * 4 + reg;
      msg[(rowbase + t) * 1024 + (size_t)h * 64 + ct * 16 + fr] = f2bf(m[reg]);
    }
  }
}

// ---------------------------------------------------------------- LayerNorm: bf16 y in -> fp32 out
__global__ __launch_bounds__(256) void layernorm_b(const ushort* __restrict__ yb,
                                                   const float* __restrict__ gamma,
                                                   const float* __restrict__ beta,
                                                   float* __restrict__ out) {
  const int row = blockIdx.x;
  const ushort* p = yb + (size_t)row * D_MODEL;
  const int tid = threadIdx.x;
  ushort4 v4 = ((const ushort4*)p)[tid];
  float y0 = bf2f(v4.x), y1 = bf2f(v4.y), y2 = bf2f(v4.z), y3 = bf2f(v4.w);
  float s = y0 + y1 + y2 + y3;
  float s2 = y0 * y0 + y1 * y1 + y2 * y2 + y3 * y3;
#pragma unroll
  for (int m = 1; m < 64; m <<= 1) {
    s += __shfl_xor(s, m);
    s2 += __shfl_xor(s2, m);
  }
  __shared__ float red[8];
  const int wave = tid >> 6, lane = tid & 63;
  if (lane == 0) { red[wave] = s; red[4 + wave] = s2; }
  __syncthreads();
  s = red[0] + red[1] + red[2] + red[3];
  s2 = red[4] + red[5] + red[6] + red[7];
  const float mu = s * (1.f / D_MODEL);
  const float var = s2 * (1.f / D_MODEL) - mu * mu;
  const float rstd = rsqrtf(var + 1e-5f);
  float4 g = *(const float4*)&gamma[tid * 4];
  float4 be = *(const float4*)&beta[tid * 4];
  float4 o;
  o.x = (y0 - mu) * rstd * g.x + be.x;
  o.y = (y1 - mu) * rstd * g.y + be.y;
  o.z = (y2 - mu) * rstd * g.z + be.z;
  o.w = (y3 - mu) * rstd * g.w + be.w;
  *(float4*)&out[(size_t)row * D_MODEL + tid * 4] = o;
}

// ---------------------------------------------------------------- launch
extern "C" void kernel_launch(void* const* d_in, const int* in_sizes, int n_in,
                              void* d_out, int out_size, void* d_ws, size_t ws_size,
                              hipStream_t stream) {
  (void)in_sizes; (void)n_in; (void)out_size; (void)ws_size;
  const float* x = (const float*)d_in[0];
  const float* wq = (const float*)d_in[1];
  const float* wkv = (const float*)d_in[2];
  const float* wo = (const float*)d_in[3];
  const float* gamma = (const float*)d_in[4];
  const float* beta = (const float*)d_in[5];
  float* out = (float*)d_out;

  ushort* xb = (ushort*)d_ws;                          // 8192x1024 bf16
  ushort* wb = xb + (size_t)8192 * 1024;               // 4096x1024: [wq;wkv;wo]
  ushort* qkvb = wb + (size_t)4096 * 1024;             // 8192x3072 (dead after attn)
  ushort* msgb = qkvb + (size_t)8192 * 3072;           // 8192x1024
  ushort* yb = qkvb;                                   // aliases qkvb (safe: attn done)

  const int M = NBATCH * SEQ_T;  // 8192

  (void)hipFuncSetAttribute(reinterpret_cast<const void*>(&gemm_3buf<0>),
                            hipFuncAttributeMaxDynamicSharedMemorySize, 147456);
  (void)hipFuncSetAttribute(reinterpret_cast<const void*>(&gemm_3buf<1>),
                            hipFuncAttributeMaxDynamicSharedMemorySize, 147456);

  // casts (x + all weights, one launch)
  cast_all<<<12288, 256, 0, stream>>>((const float4*)x, (const float4*)wq,
                                      (const float4*)wkv, (const float4*)wo, xb, wb);

  // GEMM1: qkv = x @ [wq;wkv]^T  (M=8192, N=3072, K=1024) -> 24x32 = 768 blocks = 3.0 rounds
  gemm_3buf<0><<<dim3(3072 / 128, M / 256), 512, 147456, stream>>>(xb, wb, qkvb, nullptr,
                                                                   M, 3072, 1024);

  // windowed sigmoid attention -> msg (bf16)
  attn_win_mfma<<<dim3(SEQ_T / 64, NHEADS, NBATCH), 256, 0, stream>>>(qkvb, msgb);

  // GEMM2: y = bf16(msg @ wo^T + x)  -> yb (aliases qkvb), 8x32 = 256 blocks = 1.0 round
  gemm_3buf<1><<<dim3(1024 / 128, M / 256), 512, 147456, stream>>>(msgb, wb + (size_t)3072 * 1024,
                                                                   yb, xb, M, 1024, 1024);

  // LayerNorm: yb (bf16) -> out (fp32)
  layernorm_b<<<M, 256, 0, stream>>>(yb, gamma, beta, out);
}

// Round 12
// 120.363 us; speedup vs baseline: 1.0695x; 1.0695x over previous
//
#include <hip/hip_runtime.h>
#include <hip/hip_bf16.h>

// Problem constants (B=2, T=4096, D=1024, H=16, HD=64, W=16)
#define D_MODEL 1024
#define SEQ_T   4096
#define NBATCH  2
#define NHEADS  16
#define HEAD_D  64
#define WIN     16

typedef __attribute__((ext_vector_type(8))) short bf16x8;           // MFMA A/B frag
typedef __attribute__((ext_vector_type(8))) unsigned short u16x8;   // 16B bf16 load
typedef __attribute__((ext_vector_type(4))) float f32x4;            // MFMA C/D frag

__device__ __forceinline__ unsigned short f2bf(float f) {
  union { float f; unsigned int u; } v; v.f = f;
  unsigned int r = v.u + 0x7fffu + ((v.u >> 16) & 1u);  // RNE
  return (unsigned short)(r >> 16);
}
__device__ __forceinline__ float bf2f(unsigned short u) {
  union { unsigned int u; float f; } v; v.u = ((unsigned int)u) << 16;
  return v.f;
}

#define SBAR() __builtin_amdgcn_s_barrier()
#define LGKM0() asm volatile("s_waitcnt lgkmcnt(0)" ::: "memory")
#define LGKM8() asm volatile("s_waitcnt lgkmcnt(8)" ::: "memory")
#define VMC(n) asm volatile("s_waitcnt vmcnt(" #n ")" ::: "memory")

// ---------------------------------------------------------------- merged cast kernel
__global__ __launch_bounds__(256) void cast_all(const float4* __restrict__ x,
                                                const float4* __restrict__ wq,
                                                const float4* __restrict__ wkv,
                                                const float4* __restrict__ wo,
                                                ushort* __restrict__ xb,
                                                ushort* __restrict__ wb) {
  int i = blockIdx.x * 256 + threadIdx.x;  // 0..3145727 float4 units
  float4 v;
  ushort* dst;
  if (i < 2097152) {
    v = x[i];
    dst = xb + (size_t)i * 4;
  } else {
    int j = i - 2097152;  // 0..1048575
    const float4* src;
    int off;
    if (j < 262144) { src = wq; off = 0; }
    else if (j < 786432) { src = wkv; off = 262144; }
    else { src = wo; off = 786432; }
    v = src[j - off];
    dst = wb + (size_t)j * 4;
  }
  ushort4 o;
  o.x = f2bf(v.x); o.y = f2bf(v.y); o.z = f2bf(v.z); o.w = f2bf(v.w);
  *(ushort4*)dst = o;
}

// ---------------------------------------------------------------- GEMM1: 256x192, 6-phase/2-K-tile
// (R7/R10 winner + T1 XCD swizzle.) Grid 16x32 = 512 blocks = 2.0 rounds. 8 waves 4Mx2N.
// LDS 112KiB: A[2][256][64] @0, B[2][192][64] @64KiB. Chunk-XOR swizzle both-sides.
// One stage unit per phase, placed after its region's last reader; vmcnt(4) at p3/p6.
// XCD swizzle: HW block h -> XCD h%8; logical id swz=(h%8)*64+h/8 gives each XCD a
// contiguous chunk of 64 blocks = 4 A row-bands x 16 cols -> A panel 16x-reused in its L2.
__global__ __launch_bounds__(512, 2) void gemm1_6ph(const ushort* __restrict__ A,
                                                    const ushort* __restrict__ Bt,
                                                    ushort* __restrict__ C,
                                                    int M, int N, int K) {
  extern __shared__ char smem[];  // 114688 bytes
  const int tid = threadIdx.x;
  const int wid = tid >> 6;
  const int lane = tid & 63;
  const int lin = blockIdx.y * 16 + blockIdx.x;     // 0..511
  const int swz = (lin & 7) * 64 + (lin >> 3);      // bijective (512 % 8 == 0)
  const int m0 = (swz >> 4) * 256;
  const int n0 = (swz & 15) * 192;

  const int l8 = lane >> 3;
  const int lchunk = (lane & 7) ^ (l8 & 7);
  const ushort* pA = A + (size_t)(m0 + wid * 8 + l8) * K + lchunk * 8;
  const ushort* pB = Bt + (size_t)(n0 + wid * 8 + l8) * K + lchunk * 8;

#define SA(kt, db, j0)                                                                     \
  {                                                                                        \
    _Pragma("unroll") for (int j = (j0); j < (j0) + 2; ++j) {                              \
      const ushort* gp = pA + (size_t)(j * 64) * K + (size_t)(kt) * 64;                    \
      char* lp = smem + (db) * 32768 + (j * 8 + wid) * 1024;                               \
      __builtin_amdgcn_global_load_lds((const __attribute__((address_space(1))) void*)gp,  \
                                       (__attribute__((address_space(3))) void*)lp, 16, 0, 0); \
    }                                                                                      \
  }
#define SB(kt, db)                                                                         \
  {                                                                                        \
    _Pragma("unroll") for (int j = 0; j < 3; ++j) {                                        \
      const ushort* gp = pB + (size_t)(j * 64) * K + (size_t)(kt) * 64;                    \
      char* lp = smem + 65536 + (db) * 24576 + (j * 8 + wid) * 1024;                       \
      __builtin_amdgcn_global_load_lds((const __attribute__((address_space(1))) void*)gp,  \
                                       (__attribute__((address_space(3))) void*)lp, 16, 0, 0); \
    }                                                                                      \
  }

  const int fr = lane & 15;
  const int g = lane >> 4;
  const int wr = wid >> 1;   // 0..3
  const int wc = wid & 1;    // 0..1
  int aRow[4], bRow[6], ch[2];
#pragma unroll
  for (int mi = 0; mi < 4; ++mi) aRow[mi] = (wr * 64 + mi * 16 + fr) * 128;
#pragma unroll
  for (int j = 0; j < 6; ++j) bRow[j] = (wc * 96 + j * 16 + fr) * 128;
#pragma unroll
  for (int kk = 0; kk < 2; ++kk) ch[kk] = ((kk * 4 + g) ^ (fr & 7)) * 16;

  f32x4 acc[4][6];
#pragma unroll
  for (int mi = 0; mi < 4; ++mi)
#pragma unroll
    for (int j = 0; j < 6; ++j) acc[mi][j] = (f32x4){0.f, 0.f, 0.f, 0.f};

  bf16x8 a[4][2], b[2][2];

#define RD_A(db)                                                               \
  _Pragma("unroll") for (int mi = 0; mi < 4; ++mi)                             \
    _Pragma("unroll") for (int kk = 0; kk < 2; ++kk)                           \
      a[mi][kk] = *(const bf16x8*)(smem + (db) * 32768 + aRow[mi] + ch[kk]);
#define RD_B(db, nh)                                                           \
  _Pragma("unroll") for (int ni = 0; ni < 2; ++ni)                             \
    _Pragma("unroll") for (int kk = 0; kk < 2; ++kk)                           \
      b[ni][kk] = *(const bf16x8*)(smem + 65536 + (db) * 24576 +               \
                                   bRow[(nh) * 2 + ni] + ch[kk]);
#define MM(nh)                                                                 \
  __builtin_amdgcn_s_setprio(1);                                               \
  _Pragma("unroll") for (int kk = 0; kk < 2; ++kk)                             \
    _Pragma("unroll") for (int mi = 0; mi < 4; ++mi)                           \
      _Pragma("unroll") for (int ni = 0; ni < 2; ++ni)                         \
        acc[mi][(nh) * 2 + ni] = __builtin_amdgcn_mfma_f32_16x16x32_bf16(      \
            a[mi][kk], b[ni][kk], acc[mi][(nh) * 2 + ni], 0, 0, 0);            \
  __builtin_amdgcn_s_setprio(0);

  SA(0, 0, 0); SA(0, 0, 2); SB(0, 0); SA(1, 1, 0); SA(1, 1, 2);
  VMC(4);
  SBAR();

#pragma unroll 1
  for (int i = 0; i < 8; ++i) {
    const int t1 = 2 * i + 1;
    const int t2 = (2 * i + 2 < 16) ? 2 * i + 2 : 15;
    const int t3 = (2 * i + 3 < 16) ? 2 * i + 3 : 15;
    const int d2 = t2 & 1, d3 = t3 & 1;

    RD_A(0); RD_B(0, 0);
    SB(t1, 1);
    LGKM8();
    SBAR(); LGKM0();
    MM(0);
    SBAR();

    RD_B(0, 1);
    SA(t2, d2, 0);
    SBAR(); LGKM0();
    MM(1);
    SBAR();

    RD_B(0, 2);
    SA(t2, d2, 2);
    VMC(4);
    SBAR(); LGKM0();
    MM(2);
    SBAR();

    RD_A(1); RD_B(1, 0);
    SB(t2, d2);
    LGKM8();
    SBAR(); LGKM0();
    MM(0);
    SBAR();

    RD_B(1, 1);
    SA(t3, d3, 0);
    SBAR(); LGKM0();
    MM(1);
    SBAR();

    RD_B(1, 2);
    SA(t3, d3, 2);
    VMC(4);
    SBAR(); LGKM0();
    MM(2);
    SBAR();
  }

  const int cc = lane & 15;
  const int cr4 = (lane >> 4) * 4;
#pragma unroll
  for (int mi = 0; mi < 4; ++mi)
#pragma unroll
    for (int j = 0; j < 6; ++j)
#pragma unroll
      for (int r = 0; r < 4; ++r) {
        int row = m0 + wr * 64 + mi * 16 + cr4 + r;
        int col = n0 + wc * 96 + j * 16 + cc;
        C[(size_t)row * N + col] = f2bf(acc[mi][j][r]);
      }
#undef SA
#undef SB
#undef RD_A
#undef RD_B
#undef MM
}

// ---------------------------------------------------------------- GEMM2: 256x128, bf16 resid + bf16 y out
// R5/R10 schedule + T1 XCD swizzle; 256 blocks = 1 round. Yb = bf16(acc + resid).
__global__ __launch_bounds__(512, 2) void gemm2_b(const ushort* __restrict__ A,
                                                  const ushort* __restrict__ Bt,
                                                  const ushort* __restrict__ residb,
                                                  ushort* __restrict__ Yb,
                                                  int M, int N, int K) {
  extern __shared__ char smem[];  // 98304 bytes
  const int NTK = K >> 6;
  const int tid = threadIdx.x;
  const int wid = tid >> 6;
  const int lane = tid & 63;
  const int lin = blockIdx.y * 8 + blockIdx.x;     // 0..255
  const int swz = (lin & 7) * 32 + (lin >> 3);     // bijective (256 % 8 == 0)
  const int m0 = (swz >> 3) * 256;
  const int n0 = (swz & 7) * 128;

  const int l8 = lane >> 3;
  const int lchunk = (lane & 7) ^ (l8 & 7);
  const ushort* pA = A + (size_t)(m0 + wid * 8 + l8) * K + lchunk * 8;
  const ushort* pB = Bt + (size_t)(n0 + wid * 8 + l8) * K + lchunk * 8;

#define STAGE_A(kt, db)                                                                    \
  {                                                                                        \
    _Pragma("unroll") for (int j = 0; j < 4; ++j) {                                        \
      const ushort* gp = pA + (size_t)(j * 64) * K + (size_t)(kt) * 64;                    \
      char* lp = smem + (db) * 32768 + (j * 8 + wid) * 1024;                               \
      __builtin_amdgcn_global_load_lds((const __attribute__((address_space(1))) void*)gp,  \
                                       (__attribute__((address_space(3))) void*)lp, 16, 0, 0); \
    }                                                                                      \
  }
#define STAGE_B(kt, db)                                                                    \
  {                                                                                        \
    _Pragma("unroll") for (int j = 0; j < 2; ++j) {                                        \
      const ushort* gp = pB + (size_t)(j * 64) * K + (size_t)(kt) * 64;                    \
      char* lp = smem + 65536 + (db) * 16384 + (j * 8 + wid) * 1024;                       \
      __builtin_amdgcn_global_load_lds((const __attribute__((address_space(1))) void*)gp,  \
                                       (__attribute__((address_space(3))) void*)lp, 16, 0, 0); \
    }                                                                                      \
  }

  const int fr = lane & 15;
  const int g = lane >> 4;
  const int wr = wid >> 1;
  const int wc = wid & 1;
  int aRow[4], bRow[2][2], ch[2];
#pragma unroll
  for (int mi = 0; mi < 4; ++mi) aRow[mi] = (wr * 64 + mi * 16 + fr) * 128;
#pragma unroll
  for (int nq = 0; nq < 2; ++nq)
#pragma unroll
    for (int ni = 0; ni < 2; ++ni) bRow[nq][ni] = (wc * 64 + nq * 32 + ni * 16 + fr) * 128;
#pragma unroll
  for (int kk = 0; kk < 2; ++kk) ch[kk] = ((kk * 4 + g) ^ (fr & 7)) * 16;

  f32x4 acc[2][4][2];
#pragma unroll
  for (int nq = 0; nq < 2; ++nq)
#pragma unroll
    for (int mi = 0; mi < 4; ++mi)
#pragma unroll
      for (int ni = 0; ni < 2; ++ni) acc[nq][mi][ni] = (f32x4){0.f, 0.f, 0.f, 0.f};

  bf16x8 a[4][2], b0[2][2], b1[2][2];

  STAGE_A(0, 0); STAGE_B(0, 0); STAGE_A(1, 1);
  VMC(4);
  SBAR();

#define PHASE_MFMA(nq, bfr)                                                    \
  __builtin_amdgcn_s_setprio(1);                                               \
  _Pragma("unroll") for (int kk = 0; kk < 2; ++kk)                             \
    _Pragma("unroll") for (int mi = 0; mi < 4; ++mi)                           \
      _Pragma("unroll") for (int ni = 0; ni < 2; ++ni)                         \
        acc[nq][mi][ni] = __builtin_amdgcn_mfma_f32_16x16x32_bf16(             \
            a[mi][kk], bfr[ni][kk], acc[nq][mi][ni], 0, 0, 0);                 \
  __builtin_amdgcn_s_setprio(0);

#pragma unroll 1
  for (int t = 0; t < NTK; ++t) {
    const int db = t & 1;
    const int u1 = (t + 1 < NTK) ? t + 1 : NTK - 1;
    const int u2 = (t + 2 < NTK) ? t + 2 : NTK - 1;
    const int d1 = u1 & 1, d2 = u2 & 1;
    const char* Ab = smem + db * 32768;
    const char* Bb = smem + 65536 + db * 16384;

#pragma unroll
    for (int mi = 0; mi < 4; ++mi)
#pragma unroll
      for (int kk = 0; kk < 2; ++kk)
        a[mi][kk] = *(const bf16x8*)(Ab + aRow[mi] + ch[kk]);
#pragma unroll
    for (int ni = 0; ni < 2; ++ni)
#pragma unroll
      for (int kk = 0; kk < 2; ++kk)
        b0[ni][kk] = *(const bf16x8*)(Bb + bRow[0][ni] + ch[kk]);
    STAGE_B(u1, d1);
    LGKM0();
    PHASE_MFMA(0, b0);
    VMC(2);
    SBAR();

#pragma unroll
    for (int ni = 0; ni < 2; ++ni)
#pragma unroll
      for (int kk = 0; kk < 2; ++kk)
        b1[ni][kk] = *(const bf16x8*)(Bb + bRow[1][ni] + ch[kk]);
    STAGE_A(u2, d2);
    LGKM0();
    PHASE_MFMA(1, b1);
    VMC(4);
    SBAR();
  }

  const int cc = lane & 15;
  const int cr4 = (lane >> 4) * 4;
#pragma unroll
  for (int nq = 0; nq < 2; ++nq)
#pragma unroll
    for (int mi = 0; mi < 4; ++mi)
#pragma unroll
      for (int ni = 0; ni < 2; ++ni)
#pragma unroll
        for (int r = 0; r < 4; ++r) {
          int row = m0 + wr * 64 + mi * 16 + cr4 + r;
          int col = n0 + wc * 64 + nq * 32 + ni * 16 + cc;
          size_t idx = (size_t)row * N + col;
          Yb[idx] = f2bf(acc[nq][mi][ni][r] + bf2f(residb[idx]));
        }
#undef STAGE_A
#undef STAGE_B
#undef PHASE_MFMA
}

// ---------------------------------------------------------------- sliding-window attention (MFMA band)
__global__ __launch_bounds__(256) void attn_win_mfma(const ushort* __restrict__ qkv,
                                                     ushort* __restrict__ msg) {
  __shared__ ushort Ks[80][72];
  __shared__ ushort Vt[64][88];
  __shared__ ushort Ps[4][16][40];

  const int tile = blockIdx.x;
  const int h = blockIdx.y;
  const int b = blockIdx.z;
  const int t0 = tile * 64;
  const size_t rowbase = (size_t)b * SEQ_T;
  const int tid = threadIdx.x;
  const int wave = tid >> 6;
  const int lane = tid & 63;

  for (int chunk = tid; chunk < 1280; chunk += 256) {
    int r = chunk >> 4;
    int c = (chunk & 15) * 8;
    int t = t0 - 16 + r;
    u16x8 u = {0, 0, 0, 0, 0, 0, 0, 0};
    if (t >= 0)
      u = *(const u16x8*)(qkv + (rowbase + t) * 3072 + 1024 + (size_t)h * 128 + c);
    if (c < 64) {
      *(u16x8*)&Ks[r][c] = u;
    } else {
      int d0 = c - 64;
#pragma unroll
      for (int j = 0; j < 8; ++j) Vt[d0 + j][r] = u[j];
    }
  }
  __syncthreads();

  const int fr = lane & 15;
  const int g = lane >> 4;
  const int rbase = wave * 16;

  bf16x8 qa[2];
#pragma unroll
  for (int kk = 0; kk < 2; ++kk)
    qa[kk] = *(const bf16x8*)(qkv + (rowbase + t0 + wave * 16 + fr) * 3072 +
                              (size_t)h * 64 + kk * 32 + g * 8);

  f32x4 sacc[2];
  sacc[0] = (f32x4){0.f, 0.f, 0.f, 0.f};
  sacc[1] = (f32x4){0.f, 0.f, 0.f, 0.f};
#pragma unroll
  for (int kk = 0; kk < 2; ++kk) {
#pragma unroll
    for (int nt = 0; nt < 2; ++nt) {
      bf16x8 kb = *(const bf16x8*)&Ks[rbase + nt * 16 + fr][kk * 32 + g * 8];
      sacc[nt] = __builtin_amdgcn_mfma_f32_16x16x32_bf16(qa[kk], kb, sacc[nt], 0, 0, 0);
    }
  }

#pragma unroll
  for (int nt = 0; nt < 2; ++nt) {
    int tk = t0 - 16 + rbase + nt * 16 + fr;
#pragma unroll
    for (int reg = 0; reg < 4; ++reg) {
      int t = t0 + wave * 16 + g * 4 + reg;
      float tau = 0.f;
      if (tk >= 0 && tk >= t - WIN && tk <= t - 1)
        tau = 1.f / (1.f + __expf(-sacc[nt][reg] * 0.125f));
      Ps[wave][g * 4 + reg][nt * 16 + fr] = f2bf(tau);
    }
  }
  __syncthreads();

  bf16x8 pa = *(const bf16x8*)&Ps[wave][fr][g * 8];
#pragma unroll
  for (int ct = 0; ct < 4; ++ct) {
    bf16x8 vb = *(const bf16x8*)&Vt[ct * 16 + fr][rbase + g * 8];
    f32x4 m = __builtin_amdgcn_mfma_f32_16x16x32_bf16(pa, vb, (f32x4){0.f, 0.f, 0.f, 0.f}, 0, 0, 0);
#pragma unroll
    for (int reg = 0; reg < 4; ++reg) {
      int t = t0 + wave * 16 + g * 4 + reg;
      msg[(rowbase + t) * 1024 + (size_t)h * 64 + ct * 16 + fr] = f2bf(m[reg]);
    }
  }
}

// ---------------------------------------------------------------- LayerNorm: bf16 y in -> fp32 out
__global__ __launch_bounds__(256) void layernorm_b(const ushort* __restrict__ yb,
                                                   const float* __restrict__ gamma,
                                                   const float* __restrict__ beta,
                                                   float* __restrict__ out) {
  const int row = blockIdx.x;
  const ushort* p = yb + (size_t)row * D_MODEL;
  const int tid = threadIdx.x;
  ushort4 v4 = ((const ushort4*)p)[tid];
  float y0 = bf2f(v4.x), y1 = bf2f(v4.y), y2 = bf2f(v4.z), y3 = bf2f(v4.w);
  float s = y0 + y1 + y2 + y3;
  float s2 = y0 * y0 + y1 * y1 + y2 * y2 + y3 * y3;
#pragma unroll
  for (int m = 1; m < 64; m <<= 1) {
    s += __shfl_xor(s, m);
    s2 += __shfl_xor(s2, m);
  }
  __shared__ float red[8];
  const int wave = tid >> 6, lane = tid & 63;
  if (lane == 0) { red[wave] = s; red[4 + wave] = s2; }
  __syncthreads();
  s = red[0] + red[1] + red[2] + red[3];
  s2 = red[4] + red[5] + red[6] + red[7];
  const float mu = s * (1.f / D_MODEL);
  const float var = s2 * (1.f / D_MODEL) - mu * mu;
  const float rstd = rsqrtf(var + 1e-5f);
  float4 g = *(const float4*)&gamma[tid * 4];
  float4 be = *(const float4*)&beta[tid * 4];
  float4 o;
  o.x = (y0 - mu) * rstd * g.x + be.x;
  o.y = (y1 - mu) * rstd * g.y + be.y;
  o.z = (y2 - mu) * rstd * g.z + be.z;
  o.w = (y3 - mu) * rstd * g.w + be.w;
  *(float4*)&out[(size_t)row * D_MODEL + tid * 4] = o;
}

// ---------------------------------------------------------------- launch
extern "C" void kernel_launch(void* const* d_in, const int* in_sizes, int n_in,
                              void* d_out, int out_size, void* d_ws, size_t ws_size,
                              hipStream_t stream) {
  (void)in_sizes; (void)n_in; (void)out_size; (void)ws_size;
  const float* x = (const float*)d_in[0];
  const float* wq = (const float*)d_in[1];
  const float* wkv = (const float*)d_in[2];
  const float* wo = (const float*)d_in[3];
  const float* gamma = (const float*)d_in[4];
  const float* beta = (const float*)d_in[5];
  float* out = (float*)d_out;

  ushort* xb = (ushort*)d_ws;                          // 8192x1024 bf16
  ushort* wb = xb + (size_t)8192 * 1024;               // 4096x1024: [wq;wkv;wo]
  ushort* qkvb = wb + (size_t)4096 * 1024;             // 8192x3072 (dead after attn)
  ushort* msgb = qkvb + (size_t)8192 * 3072;           // 8192x1024
  ushort* yb = qkvb;                                   // aliases qkvb (safe: attn done)

  const int M = NBATCH * SEQ_T;  // 8192

  (void)hipFuncSetAttribute(reinterpret_cast<const void*>(&gemm1_6ph),
                            hipFuncAttributeMaxDynamicSharedMemorySize, 114688);
  (void)hipFuncSetAttribute(reinterpret_cast<const void*>(&gemm2_b),
                            hipFuncAttributeMaxDynamicSharedMemorySize, 98304);

  // casts (x + all weights, one launch)
  cast_all<<<12288, 256, 0, stream>>>((const float4*)x, (const float4*)wq,
                                      (const float4*)wkv, (const float4*)wo, xb, wb);

  // GEMM1: qkv = x @ [wq;wkv]^T  (M=8192, N=3072, K=1024) -> 16x32 = 512 blocks = 2.0 rounds
  gemm1_6ph<<<dim3(3072 / 192, M / 256), 512, 114688, stream>>>(xb, wb, qkvb, M, 3072, 1024);

  // windowed sigmoid attention -> msg (bf16)
  attn_win_mfma<<<dim3(SEQ_T / 64, NHEADS, NBATCH), 256, 0, stream>>>(qkvb, msgb);

  // GEMM2: y = bf16(msg @ wo^T + x)  -> yb (aliases qkvb)
  gemm2_b<<<dim3(1024 / 128, M / 256), 512, 98304, stream>>>(msgb, wb + (size_t)3072 * 1024,
                                                             xb, yb, M, 1024, 1024);

  // LayerNorm: yb (bf16) -> out (fp32)
  layernorm_b<<<M, 256, 0, stream>>>(yb, gamma, beta, out);
}

// Round 13
// 117.280 us; speedup vs baseline: 1.0976x; 1.0263x over previous
//
#include <hip/hip_runtime.h>
#include <hip/hip_bf16.h>

// Problem constants (B=2, T=4096, D=1024, H=16, HD=64, W=16)
#define D_MODEL 1024
#define SEQ_T   4096
#define NBATCH  2
#define NHEADS  16
#define HEAD_D  64
#define WIN     16

typedef __attribute__((ext_vector_type(8))) short bf16x8;           // MFMA A/B frag
typedef __attribute__((ext_vector_type(8))) unsigned short u16x8;   // 16B bf16 load
typedef __attribute__((ext_vector_type(4))) float f32x4;            // MFMA C/D frag

__device__ __forceinline__ unsigned short f2bf(float f) {
  union { float f; unsigned int u; } v; v.f = f;
  unsigned int r = v.u + 0x7fffu + ((v.u >> 16) & 1u);  // RNE
  return (unsigned short)(r >> 16);
}
__device__ __forceinline__ float bf2f(unsigned short u) {
  union { unsigned int u; float f; } v; v.u = ((unsigned int)u) << 16;
  return v.f;
}

#define SBAR() __builtin_amdgcn_s_barrier()
#define LGKM0() asm volatile("s_waitcnt lgkmcnt(0)" ::: "memory")
#define LGKM8() asm volatile("s_waitcnt lgkmcnt(8)" ::: "memory")
#define VMC(n) asm volatile("s_waitcnt vmcnt(" #n ")" ::: "memory")

// ---------------------------------------------------------------- merged cast kernel
__global__ __launch_bounds__(256) void cast_all(const float4* __restrict__ x,
                                                const float4* __restrict__ wq,
                                                const float4* __restrict__ wkv,
                                                const float4* __restrict__ wo,
                                                ushort* __restrict__ xb,
                                                ushort* __restrict__ wb) {
  int i = blockIdx.x * 256 + threadIdx.x;  // 0..3145727 float4 units
  float4 v;
  ushort* dst;
  if (i < 2097152) {
    v = x[i];
    dst = xb + (size_t)i * 4;
  } else {
    int j = i - 2097152;  // 0..1048575
    const float4* src;
    int off;
    if (j < 262144) { src = wq; off = 0; }
    else if (j < 786432) { src = wkv; off = 262144; }
    else { src = wo; off = 786432; }
    v = src[j - off];
    dst = wb + (size_t)j * 4;
  }
  ushort4 o;
  o.x = f2bf(v.x); o.y = f2bf(v.y); o.z = f2bf(v.z); o.w = f2bf(v.w);
  *(ushort4*)dst = o;
}

// ---------------------------------------------------------------- GEMM1: 128x192, 4 waves, 2 blocks/CU
// C[m,n] = sum_k A[m,k]*Bt[n,k]; bf16 out. Grid 16x64 = 1024 blocks = 2.0 rounds @ 2/CU.
// 256 thr = 4 waves (2M x 2N): per-wave 64 rows x 96 cols (acc[4][6] — same as R7's wave).
// LDS 80KiB: A[2][128][64] @0 (16KB/buf), B[2][192][64] @32KiB (24KB/buf) -> 2 blocks/CU
// (160KiB pool) so one block's barrier/lgkm drains hide under the other's MFMA (m114).
// 3 phases/K-tile, one stage unit each; chunk-XOR swizzle both-sides:
//   p1: read A(8)+B[0..1](4); stage B-half0(t+1); lgkm8; SBAR; lgkm0; 16 MFMA; SBAR
//   p2: read B[2..3](4);      stage B-half1(t+1);        SBAR; lgkm0; 16 MFMA; SBAR
//   p3: read B[4..5](4);      stage A(t+2) [A(t) read-complete at p1-exit barrier];
//       vmcnt(4); SBAR; lgkm0; 16 MFMA; SBAR
// Per-thread FIFO (10 loads/K-tile: 3+3 B, 4 A): at p3, outstanding = A(t+1)4 + B(t+1)6 +
// A(t+2)4 = 14 -> vmcnt(4) retires tile t+1, leaves A(t+2). Prologue A(0)4,B(0)6,A(1)4 = 14
// -> vmcnt(4) matches steady state. Tail clamps restage identical bytes (benign).
// XCD swizzle: 1024 blocks, chunk 128/XCD = 8 row-bands x 16 cols -> A panel L2-resident.
__global__ __launch_bounds__(256, 2) void gemm1_2pc(const ushort* __restrict__ A,
                                                    const ushort* __restrict__ Bt,
                                                    ushort* __restrict__ C,
                                                    int M, int N, int K) {
  extern __shared__ char smem[];  // 81920 bytes
  const int NTK = K >> 6;
  const int tid = threadIdx.x;
  const int wid = tid >> 6;   // 0..3
  const int lane = tid & 63;
  const int lin = blockIdx.y * 16 + blockIdx.x;     // 0..1023
  const int swz = (lin & 7) * 128 + (lin >> 3);     // bijective (1024 % 8 == 0)
  const int m0 = (swz >> 4) * 128;
  const int n0 = (swz & 15) * 192;

  // staging lane geometry (pre-swizzled source chunk; involution c ^= row&7)
  const int l8 = lane >> 3;
  const int lchunk = (lane & 7) ^ (l8 & 7);
  const ushort* pA = A + (size_t)(m0 + wid * 8 + l8) * K + lchunk * 8;
  const ushort* pB = Bt + (size_t)(n0 + wid * 8 + l8) * K + lchunk * 8;

// A tile 128x64 = 16 segs of 8 rows; per-wave 4: seg = j*4+wid, rows j*32+wid*8.
#define SA(kt, db)                                                                         \
  {                                                                                        \
    _Pragma("unroll") for (int j = 0; j < 4; ++j) {                                        \
      const ushort* gp = pA + (size_t)(j * 32) * K + (size_t)(kt) * 64;                    \
      char* lp = smem + (db) * 16384 + (j * 4 + wid) * 1024;                               \
      __builtin_amdgcn_global_load_lds((const __attribute__((address_space(1))) void*)gp,  \
                                       (__attribute__((address_space(3))) void*)lp, 16, 0, 0); \
    }                                                                                      \
  }
// B tile 192x64 = 24 segs; per-wave 6 split into 2 units of 3: j = j0..j0+2.
#define SB(kt, db, j0)                                                                     \
  {                                                                                        \
    _Pragma("unroll") for (int j = (j0); j < (j0) + 3; ++j) {                              \
      const ushort* gp = pB + (size_t)(j * 32) * K + (size_t)(kt) * 64;                    \
      char* lp = smem + 32768 + (db) * 24576 + (j * 4 + wid) * 1024;                       \
      __builtin_amdgcn_global_load_lds((const __attribute__((address_space(1))) void*)gp,  \
                                       (__attribute__((address_space(3))) void*)lp, 16, 0, 0); \
    }                                                                                      \
  }

  // compute-side lane geometry
  const int fr = lane & 15;
  const int g = lane >> 4;
  const int wr = wid >> 1;   // 0..1 (64-row band)
  const int wc = wid & 1;    // 0..1 (96-col band)
  int aRow[4], bRow[6], ch[2];
#pragma unroll
  for (int mi = 0; mi < 4; ++mi) aRow[mi] = (wr * 64 + mi * 16 + fr) * 128;
#pragma unroll
  for (int j = 0; j < 6; ++j) bRow[j] = (wc * 96 + j * 16 + fr) * 128;
#pragma unroll
  for (int kk = 0; kk < 2; ++kk) ch[kk] = ((kk * 4 + g) ^ (fr & 7)) * 16;

  f32x4 acc[4][6];
#pragma unroll
  for (int mi = 0; mi < 4; ++mi)
#pragma unroll
    for (int j = 0; j < 6; ++j) acc[mi][j] = (f32x4){0.f, 0.f, 0.f, 0.f};

  bf16x8 a[4][2], b[2][2];

#define RD_A(db)                                                               \
  _Pragma("unroll") for (int mi = 0; mi < 4; ++mi)                             \
    _Pragma("unroll") for (int kk = 0; kk < 2; ++kk)                           \
      a[mi][kk] = *(const bf16x8*)(smem + (db) * 16384 + aRow[mi] + ch[kk]);
#define RD_B(db, nh)                                                           \
  _Pragma("unroll") for (int ni = 0; ni < 2; ++ni)                             \
    _Pragma("unroll") for (int kk = 0; kk < 2; ++kk)                           \
      b[ni][kk] = *(const bf16x8*)(smem + 32768 + (db) * 24576 +               \
                                   bRow[(nh) * 2 + ni] + ch[kk]);
#define MM(nh)                                                                 \
  __builtin_amdgcn_s_setprio(1);                                               \
  _Pragma("unroll") for (int kk = 0; kk < 2; ++kk)                             \
    _Pragma("unroll") for (int mi = 0; mi < 4; ++mi)                           \
      _Pragma("unroll") for (int ni = 0; ni < 2; ++ni)                         \
        acc[mi][(nh) * 2 + ni] = __builtin_amdgcn_mfma_f32_16x16x32_bf16(      \
            a[mi][kk], b[ni][kk], acc[mi][(nh) * 2 + ni], 0, 0, 0);            \
  __builtin_amdgcn_s_setprio(0);

  // ---- prologue: A(0),B(0),A(1) = 14 loads/thread; vmcnt(4) -> tile0 arrived, A(1) in flight
  SA(0, 0); SB(0, 0, 0); SB(0, 0, 3); SA(1, 1);
  VMC(4);
  SBAR();

#pragma unroll 1
  for (int t = 0; t < NTK; ++t) {
    const int db = t & 1;
    const int t1 = (t + 1 < NTK) ? t + 1 : NTK - 1;
    const int t2 = (t + 2 < NTK) ? t + 2 : NTK - 1;
    const int d1 = t1 & 1, d2 = t2 & 1;

    // ---- p1: read A(8) + B[0..1](4); stage B-half0(t+1)
    RD_A(db); RD_B(db, 0);
    SB(t1, d1, 0);
    LGKM8();
    SBAR(); LGKM0();
    MM(0);
    SBAR();

    // ---- p2: read B[2..3](4); stage B-half1(t+1)
    RD_B(db, 1);
    SB(t1, d1, 3);
    SBAR(); LGKM0();
    MM(1);
    SBAR();

    // ---- p3: read B[4..5](4); stage A(t+2); counted vmcnt
    RD_B(db, 2);
    SA(t2, d2);
    VMC(4);
    SBAR(); LGKM0();
    MM(2);
    SBAR();
  }

  // ---- epilogue: C/D layout col=lane&15, row=(lane>>4)*4+r
  const int cc = lane & 15;
  const int cr4 = (lane >> 4) * 4;
#pragma unroll
  for (int mi = 0; mi < 4; ++mi)
#pragma unroll
    for (int j = 0; j < 6; ++j)
#pragma unroll
      for (int r = 0; r < 4; ++r) {
        int row = m0 + wr * 64 + mi * 16 + cr4 + r;
        int col = n0 + wc * 96 + j * 16 + cc;
        C[(size_t)row * N + col] = f2bf(acc[mi][j][r]);
      }
#undef SA
#undef SB
#undef RD_A
#undef RD_B
#undef MM
}

// ---------------------------------------------------------------- GEMM2: 256x128, bf16 resid + bf16 y out
// R5/R10 schedule + T1 XCD swizzle; 256 blocks = 1 round. Yb = bf16(acc + resid).
__global__ __launch_bounds__(512, 2) void gemm2_b(const ushort* __restrict__ A,
                                                  const ushort* __restrict__ Bt,
                                                  const ushort* __restrict__ residb,
                                                  ushort* __restrict__ Yb,
                                                  int M, int N, int K) {
  extern __shared__ char smem[];  // 98304 bytes
  const int NTK = K >> 6;
  const int tid = threadIdx.x;
  const int wid = tid >> 6;
  const int lane = tid & 63;
  const int lin = blockIdx.y * 8 + blockIdx.x;     // 0..255
  const int swz = (lin & 7) * 32 + (lin >> 3);     // bijective (256 % 8 == 0)
  const int m0 = (swz >> 3) * 256;
  const int n0 = (swz & 7) * 128;

  const int l8 = lane >> 3;
  const int lchunk = (lane & 7) ^ (l8 & 7);
  const ushort* pA = A + (size_t)(m0 + wid * 8 + l8) * K + lchunk * 8;
  const ushort* pB = Bt + (size_t)(n0 + wid * 8 + l8) * K + lchunk * 8;

#define STAGE_A(kt, db)                                                                    \
  {                                                                                        \
    _Pragma("unroll") for (int j = 0; j < 4; ++j) {                                        \
      const ushort* gp = pA + (size_t)(j * 64) * K + (size_t)(kt) * 64;                    \
      char* lp = smem + (db) * 32768 + (j * 8 + wid) * 1024;                               \
      __builtin_amdgcn_global_load_lds((const __attribute__((address_space(1))) void*)gp,  \
                                       (__attribute__((address_space(3))) void*)lp, 16, 0, 0); \
    }                                                                                      \
  }
#define STAGE_B(kt, db)                                                                    \
  {                                                                                        \
    _Pragma("unroll") for (int j = 0; j < 2; ++j) {                                        \
      const ushort* gp = pB + (size_t)(j * 64) * K + (size_t)(kt) * 64;                    \
      char* lp = smem + 65536 + (db) * 16384 + (j * 8 + wid) * 1024;                       \
      __builtin_amdgcn_global_load_lds((const __attribute__((address_space(1))) void*)gp,  \
                                       (__attribute__((address_space(3))) void*)lp, 16, 0, 0); \
    }                                                                                      \
  }

  const int fr = lane & 15;
  const int g = lane >> 4;
  const int wr = wid >> 1;
  const int wc = wid & 1;
  int aRow[4], bRow[2][2], ch[2];
#pragma unroll
  for (int mi = 0; mi < 4; ++mi) aRow[mi] = (wr * 64 + mi * 16 + fr) * 128;
#pragma unroll
  for (int nq = 0; nq < 2; ++nq)
#pragma unroll
    for (int ni = 0; ni < 2; ++ni) bRow[nq][ni] = (wc * 64 + nq * 32 + ni * 16 + fr) * 128;
#pragma unroll
  for (int kk = 0; kk < 2; ++kk) ch[kk] = ((kk * 4 + g) ^ (fr & 7)) * 16;

  f32x4 acc[2][4][2];
#pragma unroll
  for (int nq = 0; nq < 2; ++nq)
#pragma unroll
    for (int mi = 0; mi < 4; ++mi)
#pragma unroll
      for (int ni = 0; ni < 2; ++ni) acc[nq][mi][ni] = (f32x4){0.f, 0.f, 0.f, 0.f};

  bf16x8 a[4][2], b0[2][2], b1[2][2];

  STAGE_A(0, 0); STAGE_B(0, 0); STAGE_A(1, 1);
  VMC(4);
  SBAR();

#define PHASE_MFMA(nq, bfr)                                                    \
  __builtin_amdgcn_s_setprio(1);                                               \
  _Pragma("unroll") for (int kk = 0; kk < 2; ++kk)                             \
    _Pragma("unroll") for (int mi = 0; mi < 4; ++mi)                           \
      _Pragma("unroll") for (int ni = 0; ni < 2; ++ni)                         \
        acc[nq][mi][ni] = __builtin_amdgcn_mfma_f32_16x16x32_bf16(             \
            a[mi][kk], bfr[ni][kk], acc[nq][mi][ni], 0, 0, 0);                 \
  __builtin_amdgcn_s_setprio(0);

#pragma unroll 1
  for (int t = 0; t < NTK; ++t) {
    const int db = t & 1;
    const int u1 = (t + 1 < NTK) ? t + 1 : NTK - 1;
    const int u2 = (t + 2 < NTK) ? t + 2 : NTK - 1;
    const int d1 = u1 & 1, d2 = u2 & 1;
    const char* Ab = smem + db * 32768;
    const char* Bb = smem + 65536 + db * 16384;

#pragma unroll
    for (int mi = 0; mi < 4; ++mi)
#pragma unroll
      for (int kk = 0; kk < 2; ++kk)
        a[mi][kk] = *(const bf16x8*)(Ab + aRow[mi] + ch[kk]);
#pragma unroll
    for (int ni = 0; ni < 2; ++ni)
#pragma unroll
      for (int kk = 0; kk < 2; ++kk)
        b0[ni][kk] = *(const bf16x8*)(Bb + bRow[0][ni] + ch[kk]);
    STAGE_B(u1, d1);
    LGKM0();
    PHASE_MFMA(0, b0);
    VMC(2);
    SBAR();

#pragma unroll
    for (int ni = 0; ni < 2; ++ni)
#pragma unroll
      for (int kk = 0; kk < 2; ++kk)
        b1[ni][kk] = *(const bf16x8*)(Bb + bRow[1][ni] + ch[kk]);
    STAGE_A(u2, d2);
    LGKM0();
    PHASE_MFMA(1, b1);
    VMC(4);
    SBAR();
  }

  const int cc = lane & 15;
  const int cr4 = (lane >> 4) * 4;
#pragma unroll
  for (int nq = 0; nq < 2; ++nq)
#pragma unroll
    for (int mi = 0; mi < 4; ++mi)
#pragma unroll
      for (int ni = 0; ni < 2; ++ni)
#pragma unroll
        for (int r = 0; r < 4; ++r) {
          int row = m0 + wr * 64 + mi * 16 + cr4 + r;
          int col = n0 + wc * 64 + nq * 32 + ni * 16 + cc;
          size_t idx = (size_t)row * N + col;
          Yb[idx] = f2bf(acc[nq][mi][ni][r] + bf2f(residb[idx]));
        }
#undef STAGE_A
#undef STAGE_B
#undef PHASE_MFMA
}

// ---------------------------------------------------------------- sliding-window attention (MFMA band)
__global__ __launch_bounds__(256) void attn_win_mfma(const ushort* __restrict__ qkv,
                                                     ushort* __restrict__ msg) {
  __shared__ ushort Ks[80][72];
  __shared__ ushort Vt[64][88];
  __shared__ ushort Ps[4][16][40];

  const int tile = blockIdx.x;
  const int h = blockIdx.y;
  const int b = blockIdx.z;
  const int t0 = tile * 64;
  const size_t rowbase = (size_t)b * SEQ_T;
  const int tid = threadIdx.x;
  const int wave = tid >> 6;
  const int lane = tid & 63;

  for (int chunk = tid; chunk < 1280; chunk += 256) {
    int r = chunk >> 4;
    int c = (chunk & 15) * 8;
    int t = t0 - 16 + r;
    u16x8 u = {0, 0, 0, 0, 0, 0, 0, 0};
    if (t >= 0)
      u = *(const u16x8*)(qkv + (rowbase + t) * 3072 + 1024 + (size_t)h * 128 + c);
    if (c < 64) {
      *(u16x8*)&Ks[r][c] = u;
    } else {
      int d0 = c - 64;
#pragma unroll
      for (int j = 0; j < 8; ++j) Vt[d0 + j][r] = u[j];
    }
  }
  __syncthreads();

  const int fr = lane & 15;
  const int g = lane >> 4;
  const int rbase = wave * 16;

  bf16x8 qa[2];
#pragma unroll
  for (int kk = 0; kk < 2; ++kk)
    qa[kk] = *(const bf16x8*)(qkv + (rowbase + t0 + wave * 16 + fr) * 3072 +
                              (size_t)h * 64 + kk * 32 + g * 8);

  f32x4 sacc[2];
  sacc[0] = (f32x4){0.f, 0.f, 0.f, 0.f};
  sacc[1] = (f32x4){0.f, 0.f, 0.f, 0.f};
#pragma unroll
  for (int kk = 0; kk < 2; ++kk) {
#pragma unroll
    for (int nt = 0; nt < 2; ++nt) {
      bf16x8 kb = *(const bf16x8*)&Ks[rbase + nt * 16 + fr][kk * 32 + g * 8];
      sacc[nt] = __builtin_amdgcn_mfma_f32_16x16x32_bf16(qa[kk], kb, sacc[nt], 0, 0, 0);
    }
  }

#pragma unroll
  for (int nt = 0; nt < 2; ++nt) {
    int tk = t0 - 16 + rbase + nt * 16 + fr;
#pragma unroll
    for (int reg = 0; reg < 4; ++reg) {
      int t = t0 + wave * 16 + g * 4 + reg;
      float tau = 0.f;
      if (tk >= 0 && tk >= t - WIN && tk <= t - 1)
        tau = 1.f / (1.f + __expf(-sacc[nt][reg] * 0.125f));
      Ps[wave][g * 4 + reg][nt * 16 + fr] = f2bf(tau);
    }
  }
  __syncthreads();

  bf16x8 pa = *(const bf16x8*)&Ps[wave][fr][g * 8];
#pragma unroll
  for (int ct = 0; ct < 4; ++ct) {
    bf16x8 vb = *(const bf16x8*)&Vt[ct * 16 + fr][rbase + g * 8];
    f32x4 m = __builtin_amdgcn_mfma_f32_16x16x32_bf16(pa, vb, (f32x4){0.f, 0.f, 0.f, 0.f}, 0, 0, 0);
#pragma unroll
    for (int reg = 0; reg < 4; ++reg) {
      int t = t0 + wave * 16 + g * 4 + reg;
      msg[(rowbase + t) * 1024 + (size_t)h * 64 + ct * 16 + fr] = f2bf(m[reg]);
    }
  }
}

// ---------------------------------------------------------------- LayerNorm: bf16 y in -> fp32 out
__global__ __launch_bounds__(256) void layernorm_b(const ushort* __restrict__ yb,
                                                   const float* __restrict__ gamma,
                                                   const float* __restrict__ beta,
                                                   float* __restrict__ out) {
  const int row = blockIdx.x;
  const ushort* p = yb + (size_t)row * D_MODEL;
  const int tid = threadIdx.x;
  ushort4 v4 = ((const ushort4*)p)[tid];
  float y0 = bf2f(v4.x), y1 = bf2f(v4.y), y2 = bf2f(v4.z), y3 = bf2f(v4.w);
  float s = y0 + y1 + y2 + y3;
  float s2 = y0 * y0 + y1 * y1 + y2 * y2 + y3 * y3;
#pragma unroll
  for (int m = 1; m < 64; m <<= 1) {
    s += __shfl_xor(s, m);
    s2 += __shfl_xor(s2, m);
  }
  __shared__ float red[8];
  const int wave = tid >> 6, lane = tid & 63;
  if (lane == 0) { red[wave] = s; red[4 + wave] = s2; }
  __syncthreads();
  s = red[0] + red[1] + red[2] + red[3];
  s2 = red[4] + red[5] + red[6] + red[7];
  const float mu = s * (1.f / D_MODEL);
  const float var = s2 * (1.f / D_MODEL) - mu * mu;
  const float rstd = rsqrtf(var + 1e-5f);
  float4 g = *(const float4*)&gamma[tid * 4];
  float4 be = *(const float4*)&beta[tid * 4];
  float4 o;
  o.x = (y0 - mu) * rstd * g.x + be.x;
  o.y = (y1 - mu) * rstd * g.y + be.y;
  o.z = (y2 - mu) * rstd * g.z + be.z;
  o.w = (y3 - mu) * rstd * g.w + be.w;
  *(float4*)&out[(size_t)row * D_MODEL + tid * 4] = o;
}

// ---------------------------------------------------------------- launch
extern "C" void kernel_launch(void* const* d_in, const int* in_sizes, int n_in,
                              void* d_out, int out_size, void* d_ws, size_t ws_size,
                              hipStream_t stream) {
  (void)in_sizes; (void)n_in; (void)out_size; (void)ws_size;
  const float* x = (const float*)d_in[0];
  const float* wq = (const float*)d_in[1];
  const float* wkv = (const float*)d_in[2];
  const float* wo = (const float*)d_in[3];
  const float* gamma = (const float*)d_in[4];
  const float* beta = (const float*)d_in[5];
  float* out = (float*)d_out;

  ushort* xb = (ushort*)d_ws;                          // 8192x1024 bf16
  ushort* wb = xb + (size_t)8192 * 1024;               // 4096x1024: [wq;wkv;wo]
  ushort* qkvb = wb + (size_t)4096 * 1024;             // 8192x3072 (dead after attn)
  ushort* msgb = qkvb + (size_t)8192 * 3072;           // 8192x1024
  ushort* yb = qkvb;                                   // aliases qkvb (safe: attn done)

  const int M = NBATCH * SEQ_T;  // 8192

  (void)hipFuncSetAttribute(reinterpret_cast<const void*>(&gemm1_2pc),
                            hipFuncAttributeMaxDynamicSharedMemorySize, 81920);
  (void)hipFuncSetAttribute(reinterpret_cast<const void*>(&gemm2_b),
                            hipFuncAttributeMaxDynamicSharedMemorySize, 98304);

  // casts (x + all weights, one launch)
  cast_all<<<12288, 256, 0, stream>>>((const float4*)x, (const float4*)wq,
                                      (const float4*)wkv, (const float4*)wo, xb, wb);

  // GEMM1: qkv = x @ [wq;wkv]^T  (M=8192, N=3072, K=1024) -> 16x64 = 1024 blocks, 2/CU
  gemm1_2pc<<<dim3(3072 / 192, M / 128), 256, 81920, stream>>>(xb, wb, qkvb, M, 3072, 1024);

  // windowed sigmoid attention -> msg (bf16)
  attn_win_mfma<<<dim3(SEQ_T / 64, NHEADS, NBATCH), 256, 0, stream>>>(qkvb, msgb);

  // GEMM2: y = bf16(msg @ wo^T + x)  -> yb (aliases qkvb)
  gemm2_b<<<dim3(1024 / 128, M / 256), 512, 98304, stream>>>(msgb, wb + (size_t)3072 * 1024,
                                                             xb, yb, M, 1024, 1024);

  // LayerNorm: yb (bf16) -> out (fp32)
  layernorm_b<<<M, 256, 0, stream>>>(yb, gamma, beta, out);
}

// Round 14
// 116.081 us; speedup vs baseline: 1.1089x; 1.0103x over previous
//
#include <hip/hip_runtime.h>
#include <hip/hip_bf16.h>

// Problem constants (B=2, T=4096, D=1024, H=16, HD=64, W=16)
#define D_MODEL 1024
#define SEQ_T   4096
#define NBATCH  2
#define NHEADS  16
#define HEAD_D  64
#define WIN     16

typedef __attribute__((ext_vector_type(8))) short bf16x8;           // MFMA A/B frag
typedef __attribute__((ext_vector_type(8))) unsigned short u16x8;   // 16B bf16 load
typedef __attribute__((ext_vector_type(4))) float f32x4;            // MFMA C/D frag

__device__ __forceinline__ unsigned short f2bf(float f) {
  union { float f; unsigned int u; } v; v.f = f;
  unsigned int r = v.u + 0x7fffu + ((v.u >> 16) & 1u);  // RNE
  return (unsigned short)(r >> 16);
}
__device__ __forceinline__ float bf2f(unsigned short u) {
  union { unsigned int u; float f; } v; v.u = ((unsigned int)u) << 16;
  return v.f;
}

#define SBAR() __builtin_amdgcn_s_barrier()
#define LGKM0() asm volatile("s_waitcnt lgkmcnt(0)" ::: "memory")
#define LGKM8() asm volatile("s_waitcnt lgkmcnt(8)" ::: "memory")
#define VMC(n) asm volatile("s_waitcnt vmcnt(" #n ")" ::: "memory")

// ---------------------------------------------------------------- merged cast kernel
__global__ __launch_bounds__(256) void cast_all(const float4* __restrict__ x,
                                                const float4* __restrict__ wq,
                                                const float4* __restrict__ wkv,
                                                const float4* __restrict__ wo,
                                                ushort* __restrict__ xb,
                                                ushort* __restrict__ wb) {
  int i = blockIdx.x * 256 + threadIdx.x;  // 0..3145727 float4 units
  float4 v;
  ushort* dst;
  if (i < 2097152) {
    v = x[i];
    dst = xb + (size_t)i * 4;
  } else {
    int j = i - 2097152;  // 0..1048575
    const float4* src;
    int off;
    if (j < 262144) { src = wq; off = 0; }
    else if (j < 786432) { src = wkv; off = 262144; }
    else { src = wo; off = 786432; }
    v = src[j - off];
    dst = wb + (size_t)j * 4;
  }
  ushort4 o;
  o.x = f2bf(v.x); o.y = f2bf(v.y); o.z = f2bf(v.z); o.w = f2bf(v.w);
  *(ushort4*)dst = o;
}

// ---------------------------------------------------------------- GEMM1: 128x192, 4 waves, 2 blocks/CU
// (R13 winner — unchanged.) Grid 16x64 = 1024 blocks = 2.0 rounds @ 2/CU.
__global__ __launch_bounds__(256, 2) void gemm1_2pc(const ushort* __restrict__ A,
                                                    const ushort* __restrict__ Bt,
                                                    ushort* __restrict__ C,
                                                    int M, int N, int K) {
  extern __shared__ char smem[];  // 81920 bytes
  const int NTK = K >> 6;
  const int tid = threadIdx.x;
  const int wid = tid >> 6;   // 0..3
  const int lane = tid & 63;
  const int lin = blockIdx.y * 16 + blockIdx.x;     // 0..1023
  const int swz = (lin & 7) * 128 + (lin >> 3);     // bijective (1024 % 8 == 0)
  const int m0 = (swz >> 4) * 128;
  const int n0 = (swz & 15) * 192;

  const int l8 = lane >> 3;
  const int lchunk = (lane & 7) ^ (l8 & 7);
  const ushort* pA = A + (size_t)(m0 + wid * 8 + l8) * K + lchunk * 8;
  const ushort* pB = Bt + (size_t)(n0 + wid * 8 + l8) * K + lchunk * 8;

#define SA(kt, db)                                                                         \
  {                                                                                        \
    _Pragma("unroll") for (int j = 0; j < 4; ++j) {                                        \
      const ushort* gp = pA + (size_t)(j * 32) * K + (size_t)(kt) * 64;                    \
      char* lp = smem + (db) * 16384 + (j * 4 + wid) * 1024;                               \
      __builtin_amdgcn_global_load_lds((const __attribute__((address_space(1))) void*)gp,  \
                                       (__attribute__((address_space(3))) void*)lp, 16, 0, 0); \
    }                                                                                      \
  }
#define SB(kt, db, j0)                                                                     \
  {                                                                                        \
    _Pragma("unroll") for (int j = (j0); j < (j0) + 3; ++j) {                              \
      const ushort* gp = pB + (size_t)(j * 32) * K + (size_t)(kt) * 64;                    \
      char* lp = smem + 32768 + (db) * 24576 + (j * 4 + wid) * 1024;                       \
      __builtin_amdgcn_global_load_lds((const __attribute__((address_space(1))) void*)gp,  \
                                       (__attribute__((address_space(3))) void*)lp, 16, 0, 0); \
    }                                                                                      \
  }

  const int fr = lane & 15;
  const int g = lane >> 4;
  const int wr = wid >> 1;   // 0..1
  const int wc = wid & 1;    // 0..1
  int aRow[4], bRow[6], ch[2];
#pragma unroll
  for (int mi = 0; mi < 4; ++mi) aRow[mi] = (wr * 64 + mi * 16 + fr) * 128;
#pragma unroll
  for (int j = 0; j < 6; ++j) bRow[j] = (wc * 96 + j * 16 + fr) * 128;
#pragma unroll
  for (int kk = 0; kk < 2; ++kk) ch[kk] = ((kk * 4 + g) ^ (fr & 7)) * 16;

  f32x4 acc[4][6];
#pragma unroll
  for (int mi = 0; mi < 4; ++mi)
#pragma unroll
    for (int j = 0; j < 6; ++j) acc[mi][j] = (f32x4){0.f, 0.f, 0.f, 0.f};

  bf16x8 a[4][2], b[2][2];

#define RD_A(db)                                                               \
  _Pragma("unroll") for (int mi = 0; mi < 4; ++mi)                             \
    _Pragma("unroll") for (int kk = 0; kk < 2; ++kk)                           \
      a[mi][kk] = *(const bf16x8*)(smem + (db) * 16384 + aRow[mi] + ch[kk]);
#define RD_B(db, nh)                                                           \
  _Pragma("unroll") for (int ni = 0; ni < 2; ++ni)                             \
    _Pragma("unroll") for (int kk = 0; kk < 2; ++kk)                           \
      b[ni][kk] = *(const bf16x8*)(smem + 32768 + (db) * 24576 +               \
                                   bRow[(nh) * 2 + ni] + ch[kk]);
#define MM(nh)                                                                 \
  __builtin_amdgcn_s_setprio(1);                                               \
  _Pragma("unroll") for (int kk = 0; kk < 2; ++kk)                             \
    _Pragma("unroll") for (int mi = 0; mi < 4; ++mi)                           \
      _Pragma("unroll") for (int ni = 0; ni < 2; ++ni)                         \
        acc[mi][(nh) * 2 + ni] = __builtin_amdgcn_mfma_f32_16x16x32_bf16(      \
            a[mi][kk], b[ni][kk], acc[mi][(nh) * 2 + ni], 0, 0, 0);            \
  __builtin_amdgcn_s_setprio(0);

  SA(0, 0); SB(0, 0, 0); SB(0, 0, 3); SA(1, 1);
  VMC(4);
  SBAR();

#pragma unroll 1
  for (int t = 0; t < NTK; ++t) {
    const int db = t & 1;
    const int t1 = (t + 1 < NTK) ? t + 1 : NTK - 1;
    const int t2 = (t + 2 < NTK) ? t + 2 : NTK - 1;
    const int d1 = t1 & 1, d2 = t2 & 1;

    RD_A(db); RD_B(db, 0);
    SB(t1, d1, 0);
    LGKM8();
    SBAR(); LGKM0();
    MM(0);
    SBAR();

    RD_B(db, 1);
    SB(t1, d1, 3);
    SBAR(); LGKM0();
    MM(1);
    SBAR();

    RD_B(db, 2);
    SA(t2, d2);
    VMC(4);
    SBAR(); LGKM0();
    MM(2);
    SBAR();
  }

  const int cc = lane & 15;
  const int cr4 = (lane >> 4) * 4;
#pragma unroll
  for (int mi = 0; mi < 4; ++mi)
#pragma unroll
    for (int j = 0; j < 6; ++j)
#pragma unroll
      for (int r = 0; r < 4; ++r) {
        int row = m0 + wr * 64 + mi * 16 + cr4 + r;
        int col = n0 + wc * 96 + j * 16 + cc;
        C[(size_t)row * N + col] = f2bf(acc[mi][j][r]);
      }
#undef SA
#undef SB
#undef RD_A
#undef RD_B
#undef MM
}

// ---------------------------------------------------------------- GEMM2: 128x128, 4 waves, 2 blocks/CU
// R13 mechanism ported: LDS 64KB (A 2x16K @0, B 2x16K @32K) -> 2 blocks/CU.
// Grid 8x64 = 512 blocks = 1.0 round @ 2/CU. 2 phases/K-tile:
//   p1: read A(8)+B-lo(4); stage B(t+1); lgkm8; SBAR; lgkm0; 16 MFMA; SBAR
//   p2: read B-hi(4);      stage A(t+2); vmcnt(4); SBAR; lgkm0; 16 MFMA; SBAR
// Per-thread FIFO (8 loads/K-tile: 4B+4A): at p2(t)-end outstanding = A(t+1)4 + B(t+1)4 +
// A(t+2)4 = 12 -> vmcnt(4) retires tile t+1, leaves A(t+2). Prologue A0,B0,A1 = 12 ✓.
// Region safety: A(t+2) over A(t) (last read p1(t), certified); B(t+1) over B(t-1) (p2(t-1)).
// Epilogue: Yb = bf16(acc + bf2f(residb)).
__global__ __launch_bounds__(256, 2) void gemm2_2pc(const ushort* __restrict__ A,
                                                    const ushort* __restrict__ Bt,
                                                    const ushort* __restrict__ residb,
                                                    ushort* __restrict__ Yb,
                                                    int M, int N, int K) {
  extern __shared__ char smem[];  // 65536 bytes
  const int NTK = K >> 6;
  const int tid = threadIdx.x;
  const int wid = tid >> 6;   // 0..3
  const int lane = tid & 63;
  const int lin = blockIdx.y * 8 + blockIdx.x;      // 0..511
  const int swz = (lin & 7) * 64 + (lin >> 3);      // bijective (512 % 8 == 0)
  const int m0 = (swz >> 3) * 128;
  const int n0 = (swz & 7) * 128;

  const int l8 = lane >> 3;
  const int lchunk = (lane & 7) ^ (l8 & 7);
  const ushort* pA = A + (size_t)(m0 + wid * 8 + l8) * K + lchunk * 8;
  const ushort* pB = Bt + (size_t)(n0 + wid * 8 + l8) * K + lchunk * 8;

// 128x64 tile = 16 segs of 8 rows; per wave 4: seg = j*4+wid, rows j*32+wid*8.
#define SA2(kt, db)                                                                        \
  {                                                                                        \
    _Pragma("unroll") for (int j = 0; j < 4; ++j) {                                        \
      const ushort* gp = pA + (size_t)(j * 32) * K + (size_t)(kt) * 64;                    \
      char* lp = smem + (db) * 16384 + (j * 4 + wid) * 1024;                               \
      __builtin_amdgcn_global_load_lds((const __attribute__((address_space(1))) void*)gp,  \
                                       (__attribute__((address_space(3))) void*)lp, 16, 0, 0); \
    }                                                                                      \
  }
#define SB2(kt, db)                                                                        \
  {                                                                                        \
    _Pragma("unroll") for (int j = 0; j < 4; ++j) {                                        \
      const ushort* gp = pB + (size_t)(j * 32) * K + (size_t)(kt) * 64;                    \
      char* lp = smem + 32768 + (db) * 16384 + (j * 4 + wid) * 1024;                       \
      __builtin_amdgcn_global_load_lds((const __attribute__((address_space(1))) void*)gp,  \
                                       (__attribute__((address_space(3))) void*)lp, 16, 0, 0); \
    }                                                                                      \
  }

  const int fr = lane & 15;
  const int g = lane >> 4;
  const int wr = wid >> 1;   // 0..1
  const int wc = wid & 1;    // 0..1
  int aRow[4], bRow[4], ch[2];
#pragma unroll
  for (int mi = 0; mi < 4; ++mi) aRow[mi] = (wr * 64 + mi * 16 + fr) * 128;
#pragma unroll
  for (int j = 0; j < 4; ++j) bRow[j] = (wc * 64 + j * 16 + fr) * 128;
#pragma unroll
  for (int kk = 0; kk < 2; ++kk) ch[kk] = ((kk * 4 + g) ^ (fr & 7)) * 16;

  f32x4 acc[4][4];
#pragma unroll
  for (int mi = 0; mi < 4; ++mi)
#pragma unroll
    for (int j = 0; j < 4; ++j) acc[mi][j] = (f32x4){0.f, 0.f, 0.f, 0.f};

  bf16x8 a[4][2], b[2][2];

#define RD_A2(db)                                                              \
  _Pragma("unroll") for (int mi = 0; mi < 4; ++mi)                             \
    _Pragma("unroll") for (int kk = 0; kk < 2; ++kk)                           \
      a[mi][kk] = *(const bf16x8*)(smem + (db) * 16384 + aRow[mi] + ch[kk]);
#define RD_B2(db, nh)                                                          \
  _Pragma("unroll") for (int ni = 0; ni < 2; ++ni)                             \
    _Pragma("unroll") for (int kk = 0; kk < 2; ++kk)                           \
      b[ni][kk] = *(const bf16x8*)(smem + 32768 + (db) * 16384 +               \
                                   bRow[(nh) * 2 + ni] + ch[kk]);
#define MM2(nh)                                                                \
  __builtin_amdgcn_s_setprio(1);                                               \
  _Pragma("unroll") for (int kk = 0; kk < 2; ++kk)                             \
    _Pragma("unroll") for (int mi = 0; mi < 4; ++mi)                           \
      _Pragma("unroll") for (int ni = 0; ni < 2; ++ni)                         \
        acc[mi][(nh) * 2 + ni] = __builtin_amdgcn_mfma_f32_16x16x32_bf16(      \
            a[mi][kk], b[ni][kk], acc[mi][(nh) * 2 + ni], 0, 0, 0);            \
  __builtin_amdgcn_s_setprio(0);

  // ---- prologue: A(0),B(0),A(1) = 12 loads/thread; vmcnt(4) -> tile0 arrived
  SA2(0, 0); SB2(0, 0); SA2(1, 1);
  VMC(4);
  SBAR();

#pragma unroll 1
  for (int t = 0; t < NTK; ++t) {
    const int db = t & 1;
    const int t1 = (t + 1 < NTK) ? t + 1 : NTK - 1;
    const int t2 = (t + 2 < NTK) ? t + 2 : NTK - 1;
    const int d1 = t1 & 1, d2 = t2 & 1;

    // ---- p1: read A(8)+B-lo(4); stage B(t+1)
    RD_A2(db); RD_B2(db, 0);
    SB2(t1, d1);
    LGKM8();
    SBAR(); LGKM0();
    MM2(0);
    SBAR();

    // ---- p2: read B-hi(4); stage A(t+2); counted vmcnt
    RD_B2(db, 1);
    SA2(t2, d2);
    VMC(4);
    SBAR(); LGKM0();
    MM2(1);
    SBAR();
  }

  // ---- epilogue
  const int cc = lane & 15;
  const int cr4 = (lane >> 4) * 4;
#pragma unroll
  for (int mi = 0; mi < 4; ++mi)
#pragma unroll
    for (int j = 0; j < 4; ++j)
#pragma unroll
      for (int r = 0; r < 4; ++r) {
        int row = m0 + wr * 64 + mi * 16 + cr4 + r;
        int col = n0 + wc * 64 + j * 16 + cc;
        size_t idx = (size_t)row * N + col;
        Yb[idx] = f2bf(acc[mi][j][r] + bf2f(residb[idx]));
      }
#undef SA2
#undef SB2
#undef RD_A2
#undef RD_B2
#undef MM2
}

// ---------------------------------------------------------------- sliding-window attention (MFMA band)
__global__ __launch_bounds__(256) void attn_win_mfma(const ushort* __restrict__ qkv,
                                                     ushort* __restrict__ msg) {
  __shared__ ushort Ks[80][72];
  __shared__ ushort Vt[64][88];
  __shared__ ushort Ps[4][16][40];

  const int tile = blockIdx.x;
  const int h = blockIdx.y;
  const int b = blockIdx.z;
  const int t0 = tile * 64;
  const size_t rowbase = (size_t)b * SEQ_T;
  const int tid = threadIdx.x;
  const int wave = tid >> 6;
  const int lane = tid & 63;

  for (int chunk = tid; chunk < 1280; chunk += 256) {
    int r = chunk >> 4;
    int c = (chunk & 15) * 8;
    int t = t0 - 16 + r;
    u16x8 u = {0, 0, 0, 0, 0, 0, 0, 0};
    if (t >= 0)
      u = *(const u16x8*)(qkv + (rowbase + t) * 3072 + 1024 + (size_t)h * 128 + c);
    if (c < 64) {
      *(u16x8*)&Ks[r][c] = u;
    } else {
      int d0 = c - 64;
#pragma unroll
      for (int j = 0; j < 8; ++j) Vt[d0 + j][r] = u[j];
    }
  }
  __syncthreads();

  const int fr = lane & 15;
  const int g = lane >> 4;
  const int rbase = wave * 16;

  bf16x8 qa[2];
#pragma unroll
  for (int kk = 0; kk < 2; ++kk)
    qa[kk] = *(const bf16x8*)(qkv + (rowbase + t0 + wave * 16 + fr) * 3072 +
                              (size_t)h * 64 + kk * 32 + g * 8);

  f32x4 sacc[2];
  sacc[0] = (f32x4){0.f, 0.f, 0.f, 0.f};
  sacc[1] = (f32x4){0.f, 0.f, 0.f, 0.f};
#pragma unroll
  for (int kk = 0; kk < 2; ++kk) {
#pragma unroll
    for (int nt = 0; nt < 2; ++nt) {
      bf16x8 kb = *(const bf16x8*)&Ks[rbase + nt * 16 + fr][kk * 32 + g * 8];
      sacc[nt] = __builtin_amdgcn_mfma_f32_16x16x32_bf16(qa[kk], kb, sacc[nt], 0, 0, 0);
    }
  }

#pragma unroll
  for (int nt = 0; nt < 2; ++nt) {
    int tk = t0 - 16 + rbase + nt * 16 + fr;
#pragma unroll
    for (int reg = 0; reg < 4; ++reg) {
      int t = t0 + wave * 16 + g * 4 + reg;
      float tau = 0.f;
      if (tk >= 0 && tk >= t - WIN && tk <= t - 1)
        tau = 1.f / (1.f + __expf(-sacc[nt][reg] * 0.125f));
      Ps[wave][g * 4 + reg][nt * 16 + fr] = f2bf(tau);
    }
  }
  __syncthreads();

  bf16x8 pa = *(const bf16x8*)&Ps[wave][fr][g * 8];
#pragma unroll
  for (int ct = 0; ct < 4; ++ct) {
    bf16x8 vb = *(const bf16x8*)&Vt[ct * 16 + fr][rbase + g * 8];
    f32x4 m = __builtin_amdgcn_mfma_f32_16x16x32_bf16(pa, vb, (f32x4){0.f, 0.f, 0.f, 0.f}, 0, 0, 0);
#pragma unroll
    for (int reg = 0; reg < 4; ++reg) {
      int t = t0 + wave * 16 + g * 4 + reg;
      msg[(rowbase + t) * 1024 + (size_t)h * 64 + ct * 16 + fr] = f2bf(m[reg]);
    }
  }
}

// ---------------------------------------------------------------- LayerNorm: bf16 y in -> fp32 out
__global__ __launch_bounds__(256) void layernorm_b(const ushort* __restrict__ yb,
                                                   const float* __restrict__ gamma,
                                                   const float* __restrict__ beta,
                                                   float* __restrict__ out) {
  const int row = blockIdx.x;
  const ushort* p = yb + (size_t)row * D_MODEL;
  const int tid = threadIdx.x;
  ushort4 v4 = ((const ushort4*)p)[tid];
  float y0 = bf2f(v4.x), y1 = bf2f(v4.y), y2 = bf2f(v4.z), y3 = bf2f(v4.w);
  float s = y0 + y1 + y2 + y3;
  float s2 = y0 * y0 + y1 * y1 + y2 * y2 + y3 * y3;
#pragma unroll
  for (int m = 1; m < 64; m <<= 1) {
    s += __shfl_xor(s, m);
    s2 += __shfl_xor(s2, m);
  }
  __shared__ float red[8];
  const int wave = tid >> 6, lane = tid & 63;
  if (lane == 0) { red[wave] = s; red[4 + wave] = s2; }
  __syncthreads();
  s = red[0] + red[1] + red[2] + red[3];
  s2 = red[4] + red[5] + red[6] + red[7];
  const float mu = s * (1.f / D_MODEL);
  const float var = s2 * (1.f / D_MODEL) - mu * mu;
  const float rstd = rsqrtf(var + 1e-5f);
  float4 g = *(const float4*)&gamma[tid * 4];
  float4 be = *(const float4*)&beta[tid * 4];
  float4 o;
  o.x = (y0 - mu) * rstd * g.x + be.x;
  o.y = (y1 - mu) * rstd * g.y + be.y;
  o.z = (y2 - mu) * rstd * g.z + be.z;
  o.w = (y3 - mu) * rstd * g.w + be.w;
  *(float4*)&out[(size_t)row * D_MODEL + tid * 4] = o;
}

// ---------------------------------------------------------------- launch
extern "C" void kernel_launch(void* const* d_in, const int* in_sizes, int n_in,
                              void* d_out, int out_size, void* d_ws, size_t ws_size,
                              hipStream_t stream) {
  (void)in_sizes; (void)n_in; (void)out_size; (void)ws_size;
  const float* x = (const float*)d_in[0];
  const float* wq = (const float*)d_in[1];
  const float* wkv = (const float*)d_in[2];
  const float* wo = (const float*)d_in[3];
  const float* gamma = (const float*)d_in[4];
  const float* beta = (const float*)d_in[5];
  float* out = (float*)d_out;

  ushort* xb = (ushort*)d_ws;                          // 8192x1024 bf16
  ushort* wb = xb + (size_t)8192 * 1024;               // 4096x1024: [wq;wkv;wo]
  ushort* qkvb = wb + (size_t)4096 * 1024;             // 8192x3072 (dead after attn)
  ushort* msgb = qkvb + (size_t)8192 * 3072;           // 8192x1024
  ushort* yb = qkvb;                                   // aliases qkvb (safe: attn done)

  const int M = NBATCH * SEQ_T;  // 8192

  (void)hipFuncSetAttribute(reinterpret_cast<const void*>(&gemm1_2pc),
                            hipFuncAttributeMaxDynamicSharedMemorySize, 81920);
  (void)hipFuncSetAttribute(reinterpret_cast<const void*>(&gemm2_2pc),
                            hipFuncAttributeMaxDynamicSharedMemorySize, 65536);

  // casts (x + all weights, one launch)
  cast_all<<<12288, 256, 0, stream>>>((const float4*)x, (const float4*)wq,
                                      (const float4*)wkv, (const float4*)wo, xb, wb);

  // GEMM1: qkv = x @ [wq;wkv]^T  (M=8192, N=3072, K=1024) -> 16x64 = 1024 blocks, 2/CU
  gemm1_2pc<<<dim3(3072 / 192, M / 128), 256, 81920, stream>>>(xb, wb, qkvb, M, 3072, 1024);

  // windowed sigmoid attention -> msg (bf16)
  attn_win_mfma<<<dim3(SEQ_T / 64, NHEADS, NBATCH), 256, 0, stream>>>(qkvb, msgb);

  // GEMM2: y = bf16(msg @ wo^T + x)  -> yb (aliases qkvb), 8x64 = 512 blocks, 2/CU
  gemm2_2pc<<<dim3(1024 / 128, M / 128), 256, 65536, stream>>>(msgb, wb + (size_t)3072 * 1024,
                                                               xb, yb, M, 1024, 1024);

  // LayerNorm: yb (bf16) -> out (fp32)
  layernorm_b<<<M, 256, 0, stream>>>(yb, gamma, beta, out);
}